// Round 4
// baseline (1140.614 us; speedup 1.0000x reference)
//
#include <hip/hip_runtime.h>
#include <cstdint>

#define B_ 16
#define L_ 2048
#define D_ 1024
#define BLROWS (B_ * L_)                 // 32768
#define QK_SCALE 0.08838834764831845f    // 1/sqrt(1024/8)

typedef unsigned short u16;
typedef __attribute__((ext_vector_type(8))) __bf16 bf16x8;
typedef __attribute__((ext_vector_type(4))) float f32x4;
typedef __attribute__((ext_vector_type(4))) unsigned int u32x4;
typedef __attribute__((ext_vector_type(4))) u16 u16x4;

__device__ __forceinline__ u16 f2bf(float f) {
  unsigned u = __builtin_bit_cast(unsigned, f);
  u += 0x7fffu + ((u >> 16) & 1u);   // RNE
  return (u16)(u >> 16);
}
__device__ __forceinline__ float bf2f(unsigned hu) {
  return __builtin_bit_cast(float, hu << 16);
}

// global -> LDS direct copy, 16B per lane. LDS dest wave-uniform base; HW adds lane*16.
__device__ __forceinline__ void gll16(const void* g, void* l) {
  auto gp = reinterpret_cast<const __attribute__((address_space(1))) unsigned int*>(
      reinterpret_cast<uintptr_t>(g));
  auto lp = reinterpret_cast<__attribute__((address_space(3))) unsigned int*>(
      reinterpret_cast<uintptr_t>(l));
  __builtin_amdgcn_global_load_lds(gp, lp, 16, 0, 0);
}

// ---------------- elementwise fp32 -> bf16 ----------------
typedef __attribute__((ext_vector_type(4))) float fv4;
__global__ void convert_bf16(const fv4* __restrict__ in, u16x4* __restrict__ out, int n4) {
  int i = blockIdx.x * blockDim.x + threadIdx.x;
  const int stride = gridDim.x * blockDim.x;
  for (; i < n4; i += stride) {
    fv4 v = in[i];
    u16x4 o;
    o.x = f2bf(v.x); o.y = f2bf(v.y); o.z = f2bf(v.z); o.w = f2bf(v.w);
    out[i] = o;
  }
}

// ---------------- 1024x1024 transpose + convert (weights) ----------------
__global__ void transpose_convert_1k(const float* __restrict__ W, u16* __restrict__ WT) {
  __shared__ float tile[32][33];
  const int bx = blockIdx.x * 32;
  const int by = blockIdx.y * 32;
  const int tx = threadIdx.x & 31;
  const int ty = threadIdx.x >> 5;
#pragma unroll
  for (int j = 0; j < 4; ++j) {
    const int r = ty + j * 8;
    tile[r][tx] = W[(size_t)(by + r) * 1024 + bx + tx];
  }
  __syncthreads();
#pragma unroll
  for (int j = 0; j < 4; ++j) {
    const int r = ty + j * 8;
    WT[(size_t)(bx + r) * 1024 + by + tx] = f2bf(tile[tx][r]);
  }
}

// ---------------- row softmax over 2048 bf16, in place ----------------
__global__ void softmax_rows(u16* __restrict__ S) {
  const size_t row = blockIdx.x;
  u32x4* p = (u32x4*)(S + row * 2048);
  const int t = threadIdx.x;
  u32x4 v = p[t];
  unsigned vv[4] = {v.x, v.y, v.z, v.w};
  float x[8];
#pragma unroll
  for (int i = 0; i < 4; ++i) {
    x[2 * i]     = bf2f(vv[i] & 0xffffu);
    x[2 * i + 1] = bf2f(vv[i] >> 16);
  }
  float m = x[0];
#pragma unroll
  for (int i = 1; i < 8; ++i) m = fmaxf(m, x[i]);
#pragma unroll
  for (int off = 32; off > 0; off >>= 1) m = fmaxf(m, __shfl_xor(m, off));
  __shared__ float red[4];
  const int w = t >> 6, l = t & 63;
  if (l == 0) red[w] = m;
  __syncthreads();
  m = fmaxf(fmaxf(red[0], red[1]), fmaxf(red[2], red[3]));
  float e[8], s = 0.f;
#pragma unroll
  for (int i = 0; i < 8; ++i) { e[i] = __expf(x[i] - m); s += e[i]; }
#pragma unroll
  for (int off = 32; off > 0; off >>= 1) s += __shfl_xor(s, off);
  __syncthreads();
  if (l == 0) red[w] = s;
  __syncthreads();
  s = red[0] + red[1] + red[2] + red[3];
  const float inv = 1.0f / s;
  unsigned oo[4];
#pragma unroll
  for (int i = 0; i < 4; ++i) {
    oo[i] = (unsigned)f2bf(e[2 * i] * inv) | ((unsigned)f2bf(e[2 * i + 1] * inv) << 16);
  }
  u32x4 o; o.x = oo[0]; o.y = oo[1]; o.z = oo[2]; o.w = oo[3];
  p[t] = o;
}

// ================= 256x256 NT GEMM, BK=32, 4-deep ring, counted vmcnt =================
// C[m][n] = sum_k A[m][k]*B[n][k].  512 threads = 8 waves (2M x 4N).
// LDS: 4 ring units x 32 KiB (A 256x32 + B 256x32, bf16).  Stage unit u+3 while
// computing unit u; boundary waits vmcnt(8) (units u+2,u+3 in flight) - T4 counted.
// Swizzle: stored 16B-slot s' of row R holds global k-slot s'^(R&3) (involution,
// pre-swizzled source + swizzled read).  T5 setprio around MFMA; T1 XCD swizzle.

template <int OUT_BF16, int BIAS_MODE, int RESID>
__global__ __launch_bounds__(512) void gemm8(
    const u16* __restrict__ A, const u16* __restrict__ Bm, void* __restrict__ Cv,
    const float* __restrict__ bias, const float* __restrict__ resid,
    int N, int K, float scale, long long sA, long long sB, long long sC,
    int gm, int gn) {
  __shared__ alignas(16) u16 lds[4][16384];   // 128 KiB: 4 units x (A 8192 | B 8192)

  // T1: bijective XCD swizzle (m204), then decode z / mtile / ntile
  const int nwg = gridDim.x;
  const int wg = blockIdx.x;
  const int q = nwg >> 3, rr = nwg & 7;
  const int xcd = wg & 7, idx = wg >> 3;
  const int wgid = (xcd < rr ? xcd * (q + 1) : rr * (q + 1) + (xcd - rr) * q) + idx;
  const int z = wgid / (gm * gn);
  const int rem = wgid - z * gm * gn;
  const int my = rem / gn;
  const int nx = rem - my * gn;
  const int m0 = my * 256, n0 = nx * 256;

  A  += (long long)z * sA;
  Bm += (long long)z * sB;

  const int t = threadIdx.x;
  const int w = t >> 6;          // wave 0..7
  const int l = t & 63;
  const int wm = w >> 2;         // 0..1 : row half (128 rows)
  const int wn = w & 3;          // 0..3 : col quarter (64 cols)
  const int lr = l & 15;
  const int lk = l >> 4;

  // ---- staging map: wave w covers rows w*32..w*32+31 of A and of B per unit.
  // lane l: rows r0=(w*32+(l>>2)), r1=r0+16; dest slot (l&3) holds global
  // k-slot (l&3)^(r&3); r&3 == (l>>2)&3 for both r0,r1.
  const int r0 = w * 32 + (l >> 2);
  const int ksrc = ((l & 3) ^ ((l >> 2) & 3)) * 8;   // u16 col offset
  const u16* pA0 = A  + (long long)(m0 + r0) * K + ksrc;
  const u16* pA1 = pA0 + 16LL * K;
  const u16* pB0 = Bm + (long long)(n0 + r0) * K + ksrc;
  const u16* pB1 = pB0 + 16LL * K;
  const int dA = w * 1024;       // wave-uniform u16 offset of A chunk within unit

#define STAGEU(U, BUFP)                           \
  gll16(pA0 + (U) * 32, (BUFP) + dA);             \
  gll16(pA1 + (U) * 32, (BUFP) + dA + 512);       \
  gll16(pB0 + (U) * 32, (BUFP) + 8192 + dA);      \
  gll16(pB1 + (U) * 32, (BUFP) + 8192 + dA + 512);

  // ---- read map: global k-slot lk of row R is at stored slot lk^(R&3); R&3==lr&3.
  const int sw8 = (lk ^ (lr & 3)) * 8;
  const int axo = (wm * 128 + lr) * 32 + sw8;           // + mf*512, mf=0..7
  const int bxo = 8192 + (wn * 64 + lr) * 32 + sw8;     // + nf*512, nf=0..3

  f32x4 acc[8][4];
#pragma unroll
  for (int i = 0; i < 8; ++i)
#pragma unroll
    for (int j = 0; j < 4; ++j) acc[i][j] = f32x4{0.f, 0.f, 0.f, 0.f};

  u16* Lb = &lds[0][0];

  // prologue: stage units 0,1,2; wait unit 0 resident (vmcnt(8): 2 units in flight)
  STAGEU(0, Lb)
  STAGEU(1, Lb + 16384)
  STAGEU(2, Lb + 32768)
  asm volatile("s_waitcnt vmcnt(8)" ::: "memory");
  __builtin_amdgcn_s_barrier();
  __builtin_amdgcn_sched_barrier(0);

  const int NT = K >> 5;
  for (int u = 0; u < NT; ++u) {
    const u16* cb = Lb + (u & 3) * 16384;        // compute buffer
    u16* sb = Lb + ((u + 3) & 3) * 16384;        // stage target (dead since u-1)

    bf16x8 af[4], bf[4], ag[4];

    // ---- phase 0: stage u+3; read af(mf0..3)+bf(all); MFMA upper half
    if (u + 3 < NT) { STAGEU(u + 3, sb) }
#pragma unroll
    for (int mf = 0; mf < 4; ++mf)
      af[mf] = __builtin_bit_cast(bf16x8, *(const u32x4*)&cb[axo + mf * 512]);
#pragma unroll
    for (int nf = 0; nf < 4; ++nf)
      bf[nf] = __builtin_bit_cast(bf16x8, *(const u32x4*)&cb[bxo + nf * 512]);
    __builtin_amdgcn_s_barrier();
    __builtin_amdgcn_s_setprio(1);
#pragma unroll
    for (int mf = 0; mf < 4; ++mf)
#pragma unroll
      for (int nf = 0; nf < 4; ++nf)
        acc[mf][nf] =
            __builtin_amdgcn_mfma_f32_16x16x32_bf16(af[mf], bf[nf], acc[mf][nf], 0, 0, 0);
    __builtin_amdgcn_s_setprio(0);
    __builtin_amdgcn_s_barrier();

    // ---- phase 1: read af(mf4..7); MFMA lower half
#pragma unroll
    for (int mf = 0; mf < 4; ++mf)
      ag[mf] = __builtin_bit_cast(bf16x8, *(const u32x4*)&cb[axo + (mf + 4) * 512]);
    __builtin_amdgcn_s_barrier();
    __builtin_amdgcn_s_setprio(1);
#pragma unroll
    for (int mf = 0; mf < 4; ++mf)
#pragma unroll
      for (int nf = 0; nf < 4; ++nf)
        acc[mf + 4][nf] =
            __builtin_amdgcn_mfma_f32_16x16x32_bf16(ag[mf], bf[nf], acc[mf + 4][nf], 0, 0, 0);
    __builtin_amdgcn_s_setprio(0);

    // ---- boundary: counted wait (next unit resident; 2 newest units stay in flight)
    if (u + 3 < NT)      { asm volatile("s_waitcnt vmcnt(8)" ::: "memory"); }
    else if (u + 2 < NT) { asm volatile("s_waitcnt vmcnt(4)" ::: "memory"); }
    else if (u + 1 < NT) { asm volatile("s_waitcnt vmcnt(0)" ::: "memory"); }
    __builtin_amdgcn_s_barrier();
    __builtin_amdgcn_sched_barrier(0);
  }

  // epilogue: acc[mi][nj] -> C row (mi&3... ) same verified mapping as before:
  // rows: wm*128 + (mi>>2)*64 + (mi&3)*16 + lk*4 + i  -- note mi here indexes
  // af order: mi=0..3 rows mf*16+lr in half 0 (rows wm*128 + mi*16 + ...),
  // mi=4..7 rows 64+ (mi-4)*16.  Equivalent linear form below.
  const int crow0 = m0 + wm * 128;
  const int ccol0 = n0 + wn * 64;
#pragma unroll
  for (int mi = 0; mi < 8; ++mi) {
#pragma unroll
    for (int i = 0; i < 4; ++i) {
      const int grow = crow0 + mi * 16 + lk * 4 + i;
#pragma unroll
      for (int nj = 0; nj < 4; ++nj) {
        const int gcol = ccol0 + nj * 16 + lr;
        float v = acc[mi][nj][i] * scale;
        if (BIAS_MODE == 1) v += bias[gcol];
        if (BIAS_MODE == 2) v += bias[grow];
        if (RESID) v += resid[(long long)grow * N + gcol];
        const long long cidx = (long long)z * sC + (long long)grow * N + gcol;
        if (OUT_BF16) ((u16*)Cv)[cidx] = f2bf(v);
        else          ((float*)Cv)[cidx] = v;
      }
    }
  }
}

// ---------------- launch ----------------
extern "C" void kernel_launch(void* const* d_in, const int* in_sizes, int n_in,
                              void* d_out, int out_size, void* d_ws, size_t ws_size,
                              hipStream_t stream) {
  const float* query = (const float*)d_in[0];
  const float* key_  = (const float*)d_in[1];
  const float* value = (const float*)d_in[2];
  const float* Wq = (const float*)d_in[3];
  const float* bq = (const float*)d_in[4];
  const float* Wk = (const float*)d_in[5];
  const float* bk = (const float*)d_in[6];
  const float* Wv = (const float*)d_in[7];
  const float* bv = (const float*)d_in[8];
  const float* Wo = (const float*)d_in[9];
  const float* bo = (const float*)d_in[10];
  float* out = (float*)d_out;

  char* ws = (char*)d_ws;
  u16* xq  = (u16*)(ws + 0);
  u16* xk  = (u16*)(ws + 67108864);
  u16* xv  = (u16*)(ws + 134217728);
  u16* wqt = (u16*)(ws + 201326592);
  u16* wkt = (u16*)(ws + 203423744);
  u16* wvt = (u16*)(ws + 205520896);
  u16* wot = (u16*)(ws + 207618048);
  u16* qb  = (u16*)(ws + 209715200);
  u16* kb  = (u16*)(ws + 276824064);
  u16* vt  = (u16*)(ws + 343932928);
  u16* sp  = (u16*)(ws + 0);           // [16][2048][2048] bf16 (reuses xq+xk)
  u16* ctx = (u16*)(ws + 134217728);   // [32768][1024] bf16 (reuses xv)

  const dim3 blk(256);
  const dim3 blk8(512);
  const int n4 = BLROWS * D_ / 4;

  convert_bf16<<<2048, blk, 0, stream>>>((const fv4*)query, (u16x4*)xq, n4);
  convert_bf16<<<2048, blk, 0, stream>>>((const fv4*)key_,  (u16x4*)xk, n4);
  convert_bf16<<<2048, blk, 0, stream>>>((const fv4*)value, (u16x4*)xv, n4);
  transpose_convert_1k<<<dim3(32, 32), blk, 0, stream>>>(Wq, wqt);
  transpose_convert_1k<<<dim3(32, 32), blk, 0, stream>>>(Wk, wkt);
  transpose_convert_1k<<<dim3(32, 32), blk, 0, stream>>>(Wv, wvt);
  transpose_convert_1k<<<dim3(32, 32), blk, 0, stream>>>(Wo, wot);

  // Q = xq @ WqT^T + bq   [32768 x 1024]  gm=128 gn=4 -> 512 wgs
  gemm8<1, 1, 0><<<dim3(512), blk8, 0, stream>>>(
      xq, wqt, qb, bq, nullptr, D_, D_, 1.0f, 0, 0, 0, 128, 4);
  // K = xk @ WkT^T + bk
  gemm8<1, 1, 0><<<dim3(512), blk8, 0, stream>>>(
      xk, wkt, kb, bk, nullptr, D_, D_, 1.0f, 0, 0, 0, 128, 4);
  // VT_b[e][l] = sum_d WvT[e][d]*value_b[l][d] + bv[e]  [1024 x 2048] x16  gm=4 gn=8
  gemm8<1, 2, 0><<<dim3(512), blk8, 0, stream>>>(
      wvt, xv, vt, bv, nullptr, L_, D_, 1.0f,
      0, (long long)L_ * D_, (long long)D_ * L_, 4, 8);
  // S_b = Q_b @ K_b^T * scale  [2048 x 2048] x16  gm=8 gn=8 -> 1024 wgs
  gemm8<1, 0, 0><<<dim3(1024), blk8, 0, stream>>>(
      qb, kb, sp, nullptr, nullptr, L_, D_, QK_SCALE,
      (long long)L_ * D_, (long long)L_ * D_, (long long)L_ * L_, 8, 8);
  // P = softmax(S) rows, in place
  softmax_rows<<<BLROWS, blk, 0, stream>>>(sp);
  // ctx_b = P_b @ VT_b^T  [2048 x 1024] x16  gm=8 gn=4 -> 512 wgs
  gemm8<1, 0, 0><<<dim3(512), blk8, 0, stream>>>(
      sp, vt, ctx, nullptr, nullptr, D_, L_, 1.0f,
      (long long)L_ * L_, (long long)D_ * L_, (long long)L_ * D_, 8, 4);
  // out = ctx @ WoT^T + bo + residual(query)  fp32 [32768 x 1024]
  gemm8<0, 1, 1><<<dim3(512), blk8, 0, stream>>>(
      ctx, wot, out, bo, query, D_, D_, 1.0f, 0, 0, 0, 128, 4);

  (void)in_sizes; (void)n_in; (void)out_size; (void)ws_size;
}

// Round 5
// 1128.746 us; speedup vs baseline: 1.0105x; 1.0105x over previous
//
#include <hip/hip_runtime.h>
#include <cstdint>

#define B_ 16
#define L_ 2048
#define D_ 1024
#define BLROWS (B_ * L_)                 // 32768
#define QK_SCALE 0.08838834764831845f    // 1/sqrt(1024/8)

typedef unsigned short u16;
typedef __attribute__((ext_vector_type(8))) __bf16 bf16x8;
typedef __attribute__((ext_vector_type(4))) float f32x4;
typedef __attribute__((ext_vector_type(4))) unsigned int u32x4;
typedef __attribute__((ext_vector_type(4))) u16 u16x4;

__device__ __forceinline__ u16 f2bf(float f) {
  unsigned u = __builtin_bit_cast(unsigned, f);
  u += 0x7fffu + ((u >> 16) & 1u);   // RNE
  return (u16)(u >> 16);
}
__device__ __forceinline__ float bf2f(unsigned hu) {
  return __builtin_bit_cast(float, hu << 16);
}

// global -> LDS direct copy, 16B per lane. LDS dest wave-uniform base; HW adds lane*16.
__device__ __forceinline__ void gll16(const void* g, void* l) {
  auto gp = reinterpret_cast<const __attribute__((address_space(1))) unsigned int*>(
      reinterpret_cast<uintptr_t>(g));
  auto lp = reinterpret_cast<__attribute__((address_space(3))) unsigned int*>(
      reinterpret_cast<uintptr_t>(l));
  __builtin_amdgcn_global_load_lds(gp, lp, 16, 0, 0);
}

// ---------------- elementwise fp32 -> bf16 ----------------
typedef __attribute__((ext_vector_type(4))) float fv4;
__global__ void convert_bf16(const fv4* __restrict__ in, u16x4* __restrict__ out, int n4) {
  int i = blockIdx.x * blockDim.x + threadIdx.x;
  const int stride = gridDim.x * blockDim.x;
  for (; i < n4; i += stride) {
    fv4 v = in[i];
    u16x4 o;
    o.x = f2bf(v.x); o.y = f2bf(v.y); o.z = f2bf(v.z); o.w = f2bf(v.w);
    out[i] = o;
  }
}

// ---------------- 1024x1024 transpose + convert (weights) ----------------
__global__ void transpose_convert_1k(const float* __restrict__ W, u16* __restrict__ WT) {
  __shared__ float tile[32][33];
  const int bx = blockIdx.x * 32;
  const int by = blockIdx.y * 32;
  const int tx = threadIdx.x & 31;
  const int ty = threadIdx.x >> 5;
#pragma unroll
  for (int j = 0; j < 4; ++j) {
    const int r = ty + j * 8;
    tile[r][tx] = W[(size_t)(by + r) * 1024 + bx + tx];
  }
  __syncthreads();
#pragma unroll
  for (int j = 0; j < 4; ++j) {
    const int r = ty + j * 8;
    WT[(size_t)(bx + r) * 1024 + by + tx] = f2bf(tile[tx][r]);
  }
}

// ---------------- row softmax over 2048 bf16, in place ----------------
__global__ void softmax_rows(u16* __restrict__ S) {
  const size_t row = blockIdx.x;
  u32x4* p = (u32x4*)(S + row * 2048);
  const int t = threadIdx.x;
  u32x4 v = p[t];
  unsigned vv[4] = {v.x, v.y, v.z, v.w};
  float x[8];
#pragma unroll
  for (int i = 0; i < 4; ++i) {
    x[2 * i]     = bf2f(vv[i] & 0xffffu);
    x[2 * i + 1] = bf2f(vv[i] >> 16);
  }
  float m = x[0];
#pragma unroll
  for (int i = 1; i < 8; ++i) m = fmaxf(m, x[i]);
#pragma unroll
  for (int off = 32; off > 0; off >>= 1) m = fmaxf(m, __shfl_xor(m, off));
  __shared__ float red[4];
  const int w = t >> 6, l = t & 63;
  if (l == 0) red[w] = m;
  __syncthreads();
  m = fmaxf(fmaxf(red[0], red[1]), fmaxf(red[2], red[3]));
  float e[8], s = 0.f;
#pragma unroll
  for (int i = 0; i < 8; ++i) { e[i] = __expf(x[i] - m); s += e[i]; }
#pragma unroll
  for (int off = 32; off > 0; off >>= 1) s += __shfl_xor(s, off);
  __syncthreads();
  if (l == 0) red[w] = s;
  __syncthreads();
  s = red[0] + red[1] + red[2] + red[3];
  const float inv = 1.0f / s;
  unsigned oo[4];
#pragma unroll
  for (int i = 0; i < 4; ++i) {
    oo[i] = (unsigned)f2bf(e[2 * i] * inv) | ((unsigned)f2bf(e[2 * i + 1] * inv) << 16);
  }
  u32x4 o; o.x = oo[0]; o.y = oo[1]; o.z = oo[2]; o.w = oo[3];
  p[t] = o;
}

// ================= 256x256 NT GEMM, BK=32, 4-deep ring, counted vmcnt =================
// C[m][n] = sum_k A[m][k]*B[n][k].  512 threads = 8 waves (2M x 4N).
// LDS: 4 ring units x 32 KiB (A 256x32 | B 256x32 bf16).  Stage unit u+3 while
// computing unit u; boundary waits vmcnt(8) (units u+2,u+3 in flight) - T4 counted.
// Layout (conflict-free, 128B period): line j (128B) holds rows 2j,2j+1; 16B-slot
// s' stores global (row r = 2j+(s8>>2), kslot s8&3) with s8 = s' ^ (j&7).
// Every aligned 8-lane ds_read_b128 group covers 8 distinct slots -> 0 conflicts.
// T5 setprio around MFMA; T1 bijective XCD grid swizzle.

template <int OUT_BF16, int BIAS_MODE, int RESID>
__global__ __launch_bounds__(512) void gemm8(
    const u16* __restrict__ A, const u16* __restrict__ Bm, void* __restrict__ Cv,
    const float* __restrict__ bias, const float* __restrict__ resid,
    int N, int K, float scale, long long sA, long long sB, long long sC,
    int gm, int gn) {
  __shared__ alignas(16) u16 lds[4][16384];   // 128 KiB: 4 units x (A 8192 u16 | B 8192 u16)

  // T1: bijective XCD swizzle (m204), then decode z / mtile / ntile
  const int nwg = gridDim.x;
  const int wg = blockIdx.x;
  const int q = nwg >> 3, rr = nwg & 7;
  const int xcd = wg & 7, idx = wg >> 3;
  const int wgid = (xcd < rr ? xcd * (q + 1) : rr * (q + 1) + (xcd - rr) * q) + idx;
  const int z = wgid / (gm * gn);
  const int rem = wgid - z * gm * gn;
  const int my = rem / gn;
  const int nx = rem - my * gn;
  const int m0 = my * 256, n0 = nx * 256;

  A  += (long long)z * sA;
  Bm += (long long)z * sB;

  const int t = threadIdx.x;
  const int w = t >> 6;          // wave 0..7
  const int l = t & 63;
  const int wm = w >> 2;         // 0..1 : row half (128 rows)
  const int wn = w & 3;          // 0..3 : col quarter (64 cols)
  const int lr = l & 15;
  const int lk = l >> 4;

  // ---- staging map (inverse swizzle): issue i covers lines i*64+(t>>3), slot t&7.
  const int s8  = (t & 7) ^ ((t >> 3) & 7);        // global slot8 for this thread
  const int rst = 2 * (t >> 3) + (s8 >> 2);        // row within 128-row half
  const int kst = (s8 & 3) * 8;                    // u16 k-offset within unit
  const u16* pA0 = A  + (long long)(m0 + rst) * K + kst;
  const u16* pA1 = A  + (long long)(m0 + 128 + rst) * K + kst;
  const u16* pB0 = Bm + (long long)(n0 + rst) * K + kst;
  const u16* pB1 = Bm + (long long)(n0 + 128 + rst) * K + kst;
  const int wbase = w * 512;     // wave-uniform u16 offset within an 8 KiB issue

#define STAGEU(U, BUFP)                              \
  gll16(pA0 + (U) * 32, (BUFP) + wbase);             \
  gll16(pA1 + (U) * 32, (BUFP) + 4096 + wbase);      \
  gll16(pB0 + (U) * 32, (BUFP) + 8192 + wbase);      \
  gll16(pB1 + (U) * 32, (BUFP) + 12288 + wbase);

  // ---- read map: frag (row=base+lr, kslot=lk) at line (base+lr)>>1,
  // slot ((lr&1)*4+lk)^(lr>>1).  base multiples of 16 keep line&7 == lr>>1.
  const int lh = lr >> 1;
  const int swz = ((((lr & 1) * 4 + lk) ^ lh) * 8);
  const int axo = (wm * 64 + lh) * 64 + swz;            // + mf*512, mf=0..7
  const int bxo = 8192 + (wn * 32 + lh) * 64 + swz;     // + nf*512, nf=0..3

  f32x4 acc[8][4];
#pragma unroll
  for (int i = 0; i < 8; ++i)
#pragma unroll
    for (int j = 0; j < 4; ++j) acc[i][j] = f32x4{0.f, 0.f, 0.f, 0.f};

  u16* Lb = &lds[0][0];

  // prologue: stage units 0,1,2; wait unit 0 resident (8 = units 1,2 in flight)
  STAGEU(0, Lb)
  STAGEU(1, Lb + 16384)
  STAGEU(2, Lb + 32768)
  asm volatile("s_waitcnt vmcnt(8)" ::: "memory");
  __builtin_amdgcn_s_barrier();
  __builtin_amdgcn_sched_barrier(0);

  const int NT = K >> 5;
  for (int u = 0; u < NT; ++u) {
    const u16* cb = Lb + (u & 3) * 16384;        // compute buffer
    u16* sb = Lb + ((u + 3) & 3) * 16384;        // stage target (dead since u-1)

    bf16x8 af[4], bf[4], ag[4];

    // ---- phase 0: stage u+3; read af(mf0..3)+bf(all); MFMA upper half
    if (u + 3 < NT) { STAGEU(u + 3, sb) }
#pragma unroll
    for (int mf = 0; mf < 4; ++mf)
      af[mf] = __builtin_bit_cast(bf16x8, *(const u32x4*)&cb[axo + mf * 512]);
#pragma unroll
    for (int nf = 0; nf < 4; ++nf)
      bf[nf] = __builtin_bit_cast(bf16x8, *(const u32x4*)&cb[bxo + nf * 512]);
    __builtin_amdgcn_s_barrier();
    __builtin_amdgcn_s_setprio(1);
#pragma unroll
    for (int mf = 0; mf < 4; ++mf)
#pragma unroll
      for (int nf = 0; nf < 4; ++nf)
        acc[mf][nf] =
            __builtin_amdgcn_mfma_f32_16x16x32_bf16(af[mf], bf[nf], acc[mf][nf], 0, 0, 0);
    __builtin_amdgcn_s_setprio(0);
    __builtin_amdgcn_s_barrier();

    // ---- phase 1: read af(mf4..7); MFMA lower half
#pragma unroll
    for (int mf = 0; mf < 4; ++mf)
      ag[mf] = __builtin_bit_cast(bf16x8, *(const u32x4*)&cb[axo + (mf + 4) * 512]);
    __builtin_amdgcn_s_barrier();
    __builtin_amdgcn_s_setprio(1);
#pragma unroll
    for (int mf = 0; mf < 4; ++mf)
#pragma unroll
      for (int nf = 0; nf < 4; ++nf)
        acc[mf + 4][nf] =
            __builtin_amdgcn_mfma_f32_16x16x32_bf16(ag[mf], bf[nf], acc[mf + 4][nf], 0, 0, 0);
    __builtin_amdgcn_s_setprio(0);

    // ---- boundary: counted wait (unit u+1 resident; 2 newest units stay in flight)
    if (u + 3 < NT)      { asm volatile("s_waitcnt vmcnt(8)" ::: "memory"); }
    else if (u + 2 < NT) { asm volatile("s_waitcnt vmcnt(4)" ::: "memory"); }
    else if (u + 1 < NT) { asm volatile("s_waitcnt vmcnt(0)" ::: "memory"); }
    __builtin_amdgcn_s_barrier();
    __builtin_amdgcn_sched_barrier(0);
  }

  // epilogue: rows wm*128 + mi*16 + lk*4 + i, cols wn*64 + nj*16 + lr (m89 map)
  const int crow0 = m0 + wm * 128;
  const int ccol0 = n0 + wn * 64;
#pragma unroll
  for (int mi = 0; mi < 8; ++mi) {
#pragma unroll
    for (int i = 0; i < 4; ++i) {
      const int grow = crow0 + mi * 16 + lk * 4 + i;
#pragma unroll
      for (int nj = 0; nj < 4; ++nj) {
        const int gcol = ccol0 + nj * 16 + lr;
        float v = acc[mi][nj][i] * scale;
        if (BIAS_MODE == 1) v += bias[gcol];
        if (BIAS_MODE == 2) v += bias[grow];
        if (RESID) v += resid[(long long)grow * N + gcol];
        const long long cidx = (long long)z * sC + (long long)grow * N + gcol;
        if (OUT_BF16) ((u16*)Cv)[cidx] = f2bf(v);
        else          ((float*)Cv)[cidx] = v;
      }
    }
  }
}

// ---------------- launch ----------------
extern "C" void kernel_launch(void* const* d_in, const int* in_sizes, int n_in,
                              void* d_out, int out_size, void* d_ws, size_t ws_size,
                              hipStream_t stream) {
  const float* query = (const float*)d_in[0];
  const float* key_  = (const float*)d_in[1];
  const float* value = (const float*)d_in[2];
  const float* Wq = (const float*)d_in[3];
  const float* bq = (const float*)d_in[4];
  const float* Wk = (const float*)d_in[5];
  const float* bk = (const float*)d_in[6];
  const float* Wv = (const float*)d_in[7];
  const float* bv = (const float*)d_in[8];
  const float* Wo = (const float*)d_in[9];
  const float* bo = (const float*)d_in[10];
  float* out = (float*)d_out;

  char* ws = (char*)d_ws;
  u16* xq  = (u16*)(ws + 0);
  u16* xk  = (u16*)(ws + 67108864);
  u16* xv  = (u16*)(ws + 134217728);
  u16* wqt = (u16*)(ws + 201326592);
  u16* wkt = (u16*)(ws + 203423744);
  u16* wvt = (u16*)(ws + 205520896);
  u16* wot = (u16*)(ws + 207618048);
  u16* qb  = (u16*)(ws + 209715200);
  u16* kb  = (u16*)(ws + 276824064);
  u16* vt  = (u16*)(ws + 343932928);
  u16* sp  = (u16*)(ws + 0);           // [16][2048][2048] bf16 (reuses xq+xk)
  u16* ctx = (u16*)(ws + 134217728);   // [32768][1024] bf16 (reuses xv)

  const dim3 blk(256);
  const dim3 blk8(512);
  const int n4 = BLROWS * D_ / 4;

  convert_bf16<<<2048, blk, 0, stream>>>((const fv4*)query, (u16x4*)xq, n4);
  convert_bf16<<<2048, blk, 0, stream>>>((const fv4*)key_,  (u16x4*)xk, n4);
  convert_bf16<<<2048, blk, 0, stream>>>((const fv4*)value, (u16x4*)xv, n4);
  transpose_convert_1k<<<dim3(32, 32), blk, 0, stream>>>(Wq, wqt);
  transpose_convert_1k<<<dim3(32, 32), blk, 0, stream>>>(Wk, wkt);
  transpose_convert_1k<<<dim3(32, 32), blk, 0, stream>>>(Wv, wvt);
  transpose_convert_1k<<<dim3(32, 32), blk, 0, stream>>>(Wo, wot);

  // Q = xq @ WqT^T + bq   [32768 x 1024]  gm=128 gn=4 -> 512 wgs
  gemm8<1, 1, 0><<<dim3(512), blk8, 0, stream>>>(
      xq, wqt, qb, bq, nullptr, D_, D_, 1.0f, 0, 0, 0, 128, 4);
  // K = xk @ WkT^T + bk
  gemm8<1, 1, 0><<<dim3(512), blk8, 0, stream>>>(
      xk, wkt, kb, bk, nullptr, D_, D_, 1.0f, 0, 0, 0, 128, 4);
  // VT_b[e][l] = sum_d WvT[e][d]*value_b[l][d] + bv[e]  [1024 x 2048] x16  gm=4 gn=8
  gemm8<1, 2, 0><<<dim3(512), blk8, 0, stream>>>(
      wvt, xv, vt, bv, nullptr, L_, D_, 1.0f,
      0, (long long)L_ * D_, (long long)D_ * L_, 4, 8);
  // S_b = Q_b @ K_b^T * scale  [2048 x 2048] x16  gm=8 gn=8 -> 1024 wgs
  gemm8<1, 0, 0><<<dim3(1024), blk8, 0, stream>>>(
      qb, kb, sp, nullptr, nullptr, L_, D_, QK_SCALE,
      (long long)L_ * D_, (long long)L_ * D_, (long long)L_ * L_, 8, 8);
  // P = softmax(S) rows, in place
  softmax_rows<<<BLROWS, blk, 0, stream>>>(sp);
  // ctx_b = P_b @ VT_b^T  [2048 x 1024] x16  gm=8 gn=4 -> 512 wgs
  gemm8<1, 0, 0><<<dim3(512), blk8, 0, stream>>>(
      sp, vt, ctx, nullptr, nullptr, D_, L_, 1.0f,
      (long long)L_ * L_, (long long)D_ * L_, (long long)L_ * D_, 8, 4);
  // out = ctx @ WoT^T + bo + residual(query)  fp32 [32768 x 1024]
  gemm8<0, 1, 1><<<dim3(512), blk8, 0, stream>>>(
      ctx, wot, out, bo, query, D_, D_, 1.0f, 0, 0, 0, 128, 4);

  (void)in_sizes; (void)n_in; (void)out_size; (void)ws_size;
}

// Round 8
// 1064.680 us; speedup vs baseline: 1.0713x; 1.0602x over previous
//
#include <hip/hip_runtime.h>
#include <cstdint>

#define B_ 16
#define L_ 2048
#define D_ 1024
#define BLROWS (B_ * L_)                 // 32768
#define QK_SCALE 0.08838834764831845f    // 1/sqrt(1024/8)

typedef unsigned short u16;
typedef __attribute__((ext_vector_type(8))) __bf16 bf16x8;
typedef __attribute__((ext_vector_type(4))) float f32x4;
typedef __attribute__((ext_vector_type(4))) unsigned int u32x4;
typedef __attribute__((ext_vector_type(4))) u16 u16x4;

__device__ __forceinline__ u16 f2bf(float f) {
  unsigned u = __builtin_bit_cast(unsigned, f);
  u += 0x7fffu + ((u >> 16) & 1u);   // RNE
  return (u16)(u >> 16);
}
__device__ __forceinline__ float bf2f(unsigned hu) {
  return __builtin_bit_cast(float, hu << 16);
}

// global -> LDS direct copy, 16B per lane. LDS dest wave-uniform base; HW adds lane*16.
__device__ __forceinline__ void gll16(const void* g, void* l) {
  auto gp = reinterpret_cast<const __attribute__((address_space(1))) unsigned int*>(
      reinterpret_cast<uintptr_t>(g));
  auto lp = reinterpret_cast<__attribute__((address_space(3))) unsigned int*>(
      reinterpret_cast<uintptr_t>(l));
  __builtin_amdgcn_global_load_lds(gp, lp, 16, 0, 0);
}

// ---------------- elementwise fp32 -> bf16 ----------------
typedef __attribute__((ext_vector_type(4))) float fv4;
__global__ void convert_bf16(const fv4* __restrict__ in, u16x4* __restrict__ out, int n4) {
  int i = blockIdx.x * blockDim.x + threadIdx.x;
  const int stride = gridDim.x * blockDim.x;
  for (; i < n4; i += stride) {
    fv4 v = in[i];
    u16x4 o;
    o.x = f2bf(v.x); o.y = f2bf(v.y); o.z = f2bf(v.z); o.w = f2bf(v.w);
    out[i] = o;
  }
}

// ---------------- 1024x1024 transpose + convert (weights) ----------------
__global__ void transpose_convert_1k(const float* __restrict__ W, u16* __restrict__ WT) {
  __shared__ float tile[32][33];
  const int bx = blockIdx.x * 32;
  const int by = blockIdx.y * 32;
  const int tx = threadIdx.x & 31;
  const int ty = threadIdx.x >> 5;
#pragma unroll
  for (int j = 0; j < 4; ++j) {
    const int r = ty + j * 8;
    tile[r][tx] = W[(size_t)(by + r) * 1024 + bx + tx];
  }
  __syncthreads();
#pragma unroll
  for (int j = 0; j < 4; ++j) {
    const int r = ty + j * 8;
    WT[(size_t)(bx + r) * 1024 + by + tx] = f2bf(tile[tx][r]);
  }
}

// ---------------- row softmax over 2048 bf16, in place ----------------
__global__ void softmax_rows(u16* __restrict__ S) {
  const size_t row = blockIdx.x;
  u32x4* p = (u32x4*)(S + row * 2048);
  const int t = threadIdx.x;
  u32x4 v = p[t];
  unsigned vv[4] = {v.x, v.y, v.z, v.w};
  float x[8];
#pragma unroll
  for (int i = 0; i < 4; ++i) {
    x[2 * i]     = bf2f(vv[i] & 0xffffu);
    x[2 * i + 1] = bf2f(vv[i] >> 16);
  }
  float m = x[0];
#pragma unroll
  for (int i = 1; i < 8; ++i) m = fmaxf(m, x[i]);
#pragma unroll
  for (int off = 32; off > 0; off >>= 1) m = fmaxf(m, __shfl_xor(m, off));
  __shared__ float red[4];
  const int w = t >> 6, l = t & 63;
  if (l == 0) red[w] = m;
  __syncthreads();
  m = fmaxf(fmaxf(red[0], red[1]), fmaxf(red[2], red[3]));
  float e[8], s = 0.f;
#pragma unroll
  for (int i = 0; i < 8; ++i) { e[i] = __expf(x[i] - m); s += e[i]; }
#pragma unroll
  for (int off = 32; off > 0; off >>= 1) s += __shfl_xor(s, off);
  __syncthreads();
  if (l == 0) red[w] = s;
  __syncthreads();
  s = red[0] + red[1] + red[2] + red[3];
  const float inv = 1.0f / s;
  unsigned oo[4];
#pragma unroll
  for (int i = 0; i < 4; ++i) {
    oo[i] = (unsigned)f2bf(e[2 * i] * inv) | ((unsigned)f2bf(e[2 * i + 1] * inv) << 16);
  }
  u32x4 o; o.x = oo[0]; o.y = oo[1]; o.z = oo[2]; o.w = oo[3];
  p[t] = o;
}

// ========== 256x256 NT GEMM, BK=64, 2-dbuf, 4-phase interleave, counted vmcnt ==========
// C[m][n] = sum_k A[m][k]*B[n][k].  512 threads = 8 waves (2M x 4N), wave owns 128x64.
// LDS: 2 bufs x 64 KiB (A[256][64] | B[256][64] bf16).  Tile t computed from buf[t&1];
// tile t+2 staged into the SAME buffer during tile t's phases 3-4 (all LDS reads of
// the buffer are register-complete by then: each phase's ds_reads feed that phase's
// MFMA, so lgkm drains before the post-phase barrier).  Boundary waits vmcnt(8)
// (tile t+2's 8 loads stay in flight) - T4 counted, lead 5-7 phases.
// Swizzle (0-conflict, verified family): row r = one 128B line; stored 16B-slot s'
// holds k-chunk s'^(r&7); staging uses the inverse on the global source (rule #21).
// Quadrant order (0,0)->(1,0)->(1,1)->(0,1).  T5 setprio; T1 bijective XCD swizzle.

template <int OUT_BF16, int BIAS_MODE, int RESID>
__global__ __launch_bounds__(512) void gemm8(
    const u16* __restrict__ A, const u16* __restrict__ Bm, void* __restrict__ Cv,
    const float* __restrict__ bias, const float* __restrict__ resid,
    int N, int K, float scale, long long sA, long long sB, long long sC,
    int gm, int gn) {
  __shared__ alignas(16) u16 lds[2][32768];   // 128 KiB: 2 x (A 16384 u16 | B 16384 u16)

  // T1: bijective XCD swizzle (m204), then decode z / mtile / ntile
  const int nwg = gridDim.x;
  const int wg = blockIdx.x;
  const int q = nwg >> 3, rr = nwg & 7;
  const int xcd = wg & 7, idx = wg >> 3;
  const int wgid = (xcd < rr ? xcd * (q + 1) : rr * (q + 1) + (xcd - rr) * q) + idx;
  const int z = wgid / (gm * gn);
  const int rem = wgid - z * gm * gn;
  const int my = rem / gn;
  const int nx = rem - my * gn;
  const int m0 = my * 256, n0 = nx * 256;

  A  += (long long)z * sA;
  Bm += (long long)z * sB;

  const int t = threadIdx.x;
  const int w = t >> 6;          // wave 0..7
  const int l = t & 63;
  const int wm = w >> 2;         // 0..1 : row half (128 rows)
  const int wn = w & 3;          // 0..3 : col quarter (64 cols)
  const int lr = l & 15;
  const int lk = l >> 4;

  // ---- staging map (inverse swizzle): issue i covers rows i*64 + (t>>3);
  // dest slot t&7 holds k-chunk (t&7)^(row&7).
  const int rl = t >> 3;                               // 0..63, row&7 == rl&7
  const int kc8 = ((t & 7) ^ (rl & 7)) * 8;            // u16 k-offset of the chunk
  const u16* sa = A  + (long long)(m0 + rl) * K + kc8;
  const u16* sb = Bm + (long long)(n0 + rl) * K + kc8;
  const long long rK = 64LL * K;
  const int wbase = w * 512;     // wave-uniform u16 offset within an 8 KiB issue

#define STAGE_A(TT, BUF)                                        \
  gll16(sa + 0 * rK + (TT) * 64, (BUF) +     0 + wbase);        \
  gll16(sa + 1 * rK + (TT) * 64, (BUF) +  4096 + wbase);        \
  gll16(sa + 2 * rK + (TT) * 64, (BUF) +  8192 + wbase);        \
  gll16(sa + 3 * rK + (TT) * 64, (BUF) + 12288 + wbase);
#define STAGE_B(TT, BUF)                                        \
  gll16(sb + 0 * rK + (TT) * 64, (BUF) + 16384 + wbase);        \
  gll16(sb + 1 * rK + (TT) * 64, (BUF) + 20480 + wbase);        \
  gll16(sb + 2 * rK + (TT) * 64, (BUF) + 24576 + wbase);        \
  gll16(sb + 3 * rK + (TT) * 64, (BUF) + 28672 + wbase);

  // ---- read map: row r, k-chunk c=kk*4+lk at u16 addr r*64 + (c^(r&7))*8; r&7==lr&7.
  const int sw = lr & 7;
  const int c0 = ((0 + lk) ^ sw) * 8;                  // kk=0
  const int c1 = ((4 + lk) ^ sw) * 8;                  // kk=1
  const int a0 = (wm * 128 + lr) * 64;                 // af: +mf*1024 ; ag: +4096
  const int b0 = 16384 + (wn * 64 + lr) * 64;          // bf0: +nf*1024 ; bf1: +2048

  f32x4 acc[8][4];
#pragma unroll
  for (int i = 0; i < 8; ++i)
#pragma unroll
    for (int j = 0; j < 4; ++j) acc[i][j] = f32x4{0.f, 0.f, 0.f, 0.f};

  // prologue: stage tiles 0,1; wait tile 0 resident (tile 1's 8 loads in flight)
  STAGE_A(0, &lds[0][0])
  STAGE_B(0, &lds[0][0])
  STAGE_A(1, &lds[1][0])
  STAGE_B(1, &lds[1][0])
  asm volatile("s_waitcnt vmcnt(8)" ::: "memory");
  __builtin_amdgcn_s_barrier();
  __builtin_amdgcn_sched_barrier(0);

  const int NT = K >> 6;
  for (int u = 0; u < NT; ++u) {
    u16* cb = &lds[u & 1][0];            // compute buffer == stage target for tile u+2
    const bool pf = (u + 2 < NT);

    bf16x8 af[4][2], ag[4][2], b0f[2][2], b1f[2][2];

    // ---- phase 1: read af + bf0; MFMA quad(0,0)
#pragma unroll
    for (int mf = 0; mf < 4; ++mf) {
      af[mf][0] = __builtin_bit_cast(bf16x8, *(const u32x4*)&cb[a0 + mf * 1024 + c0]);
      af[mf][1] = __builtin_bit_cast(bf16x8, *(const u32x4*)&cb[a0 + mf * 1024 + c1]);
    }
#pragma unroll
    for (int nf = 0; nf < 2; ++nf) {
      b0f[nf][0] = __builtin_bit_cast(bf16x8, *(const u32x4*)&cb[b0 + nf * 1024 + c0]);
      b0f[nf][1] = __builtin_bit_cast(bf16x8, *(const u32x4*)&cb[b0 + nf * 1024 + c1]);
    }
    __builtin_amdgcn_s_barrier();
    __builtin_amdgcn_s_setprio(1);
#pragma unroll
    for (int mf = 0; mf < 4; ++mf)
#pragma unroll
      for (int nf = 0; nf < 2; ++nf)
#pragma unroll
        for (int kk = 0; kk < 2; ++kk)
          acc[mf][nf] = __builtin_amdgcn_mfma_f32_16x16x32_bf16(
              af[mf][kk], b0f[nf][kk], acc[mf][nf], 0, 0, 0);
    __builtin_amdgcn_s_setprio(0);
    __builtin_amdgcn_s_barrier();

    // ---- phase 2: read ag; MFMA quad(1,0)
#pragma unroll
    for (int mf = 0; mf < 4; ++mf) {
      ag[mf][0] = __builtin_bit_cast(bf16x8, *(const u32x4*)&cb[a0 + 4096 + mf * 1024 + c0]);
      ag[mf][1] = __builtin_bit_cast(bf16x8, *(const u32x4*)&cb[a0 + 4096 + mf * 1024 + c1]);
    }
    __builtin_amdgcn_s_barrier();
    __builtin_amdgcn_s_setprio(1);
#pragma unroll
    for (int mf = 0; mf < 4; ++mf)
#pragma unroll
      for (int nf = 0; nf < 2; ++nf)
#pragma unroll
        for (int kk = 0; kk < 2; ++kk)
          acc[mf + 4][nf] = __builtin_amdgcn_mfma_f32_16x16x32_bf16(
              ag[mf][kk], b0f[nf][kk], acc[mf + 4][nf], 0, 0, 0);
    __builtin_amdgcn_s_setprio(0);
    __builtin_amdgcn_s_barrier();

    // ---- phase 3: stage A(tile u+2) into A-region (all A-reads reg-complete);
    //              read bf1 (B-region, disjoint); MFMA quad(1,1)
    if (pf) { STAGE_A(u + 2, cb) }
#pragma unroll
    for (int nf = 0; nf < 2; ++nf) {
      b1f[nf][0] = __builtin_bit_cast(bf16x8, *(const u32x4*)&cb[b0 + 2048 + nf * 1024 + c0]);
      b1f[nf][1] = __builtin_bit_cast(bf16x8, *(const u32x4*)&cb[b0 + 2048 + nf * 1024 + c1]);
    }
    __builtin_amdgcn_s_barrier();
    __builtin_amdgcn_s_setprio(1);
#pragma unroll
    for (int mf = 0; mf < 4; ++mf)
#pragma unroll
      for (int nf = 0; nf < 2; ++nf)
#pragma unroll
        for (int kk = 0; kk < 2; ++kk)
          acc[mf + 4][nf + 2] = __builtin_amdgcn_mfma_f32_16x16x32_bf16(
              ag[mf][kk], b1f[nf][kk], acc[mf + 4][nf + 2], 0, 0, 0);
    __builtin_amdgcn_s_setprio(0);
    __builtin_amdgcn_s_barrier();

    // ---- phase 4: stage B(tile u+2) (all B-reads reg-complete); MFMA quad(0,1)
    if (pf) { STAGE_B(u + 2, cb) }
    __builtin_amdgcn_s_setprio(1);
#pragma unroll
    for (int mf = 0; mf < 4; ++mf)
#pragma unroll
      for (int nf = 0; nf < 2; ++nf)
#pragma unroll
        for (int kk = 0; kk < 2; ++kk)
          acc[mf][nf + 2] = __builtin_amdgcn_mfma_f32_16x16x32_bf16(
              af[mf][kk], b1f[nf][kk], acc[mf][nf + 2], 0, 0, 0);
    __builtin_amdgcn_s_setprio(0);

    // ---- boundary: counted wait - tile u+1 resident, tile u+2's 8 loads in flight
    if (pf)                { asm volatile("s_waitcnt vmcnt(8)" ::: "memory"); }
    else if (u + 1 < NT)   { asm volatile("s_waitcnt vmcnt(0)" ::: "memory"); }
    __builtin_amdgcn_s_barrier();
    __builtin_amdgcn_sched_barrier(0);
  }

  // epilogue: rows wm*128 + mi*16 + lk*4 + i, cols wn*64 + nj*16 + lr (m89 map)
  const int crow0 = m0 + wm * 128;
  const int ccol0 = n0 + wn * 64;
#pragma unroll
  for (int mi = 0; mi < 8; ++mi) {
#pragma unroll
    for (int i = 0; i < 4; ++i) {
      const int grow = crow0 + mi * 16 + lk * 4 + i;
#pragma unroll
      for (int nj = 0; nj < 4; ++nj) {
        const int gcol = ccol0 + nj * 16 + lr;
        float v = acc[mi][nj][i] * scale;
        if (BIAS_MODE == 1) v += bias[gcol];
        if (BIAS_MODE == 2) v += bias[grow];
        if (RESID) v += resid[(long long)grow * N + gcol];
        const long long cidx = (long long)z * sC + (long long)grow * N + gcol;
        if (OUT_BF16) ((u16*)Cv)[cidx] = f2bf(v);
        else          ((float*)Cv)[cidx] = v;
      }
    }
  }
}

// ---------------- launch ----------------
extern "C" void kernel_launch(void* const* d_in, const int* in_sizes, int n_in,
                              void* d_out, int out_size, void* d_ws, size_t ws_size,
                              hipStream_t stream) {
  const float* query = (const float*)d_in[0];
  const float* key_  = (const float*)d_in[1];
  const float* value = (const float*)d_in[2];
  const float* Wq = (const float*)d_in[3];
  const float* bq = (const float*)d_in[4];
  const float* Wk = (const float*)d_in[5];
  const float* bk = (const float*)d_in[6];
  const float* Wv = (const float*)d_in[7];
  const float* bv = (const float*)d_in[8];
  const float* Wo = (const float*)d_in[9];
  const float* bo = (const float*)d_in[10];
  float* out = (float*)d_out;

  char* ws = (char*)d_ws;
  u16* xq  = (u16*)(ws + 0);
  u16* xk  = (u16*)(ws + 67108864);
  u16* xv  = (u16*)(ws + 134217728);
  u16* wqt = (u16*)(ws + 201326592);
  u16* wkt = (u16*)(ws + 203423744);
  u16* wvt = (u16*)(ws + 205520896);
  u16* wot = (u16*)(ws + 207618048);
  u16* qb  = (u16*)(ws + 209715200);
  u16* kb  = (u16*)(ws + 276824064);
  u16* vt  = (u16*)(ws + 343932928);
  u16* sp  = (u16*)(ws + 0);           // [16][2048][2048] bf16 (reuses xq+xk)
  u16* ctx = (u16*)(ws + 134217728);   // [32768][1024] bf16 (reuses xv)

  const dim3 blk(256);
  const dim3 blk8(512);
  const int n4 = BLROWS * D_ / 4;

  convert_bf16<<<2048, blk, 0, stream>>>((const fv4*)query, (u16x4*)xq, n4);
  convert_bf16<<<2048, blk, 0, stream>>>((const fv4*)key_,  (u16x4*)xk, n4);
  convert_bf16<<<2048, blk, 0, stream>>>((const fv4*)value, (u16x4*)xv, n4);
  transpose_convert_1k<<<dim3(32, 32), blk, 0, stream>>>(Wq, wqt);
  transpose_convert_1k<<<dim3(32, 32), blk, 0, stream>>>(Wk, wkt);
  transpose_convert_1k<<<dim3(32, 32), blk, 0, stream>>>(Wv, wvt);
  transpose_convert_1k<<<dim3(32, 32), blk, 0, stream>>>(Wo, wot);

  // Q = xq @ WqT^T + bq   [32768 x 1024]  gm=128 gn=4 -> 512 wgs
  gemm8<1, 1, 0><<<dim3(512), blk8, 0, stream>>>(
      xq, wqt, qb, bq, nullptr, D_, D_, 1.0f, 0, 0, 0, 128, 4);
  // K = xk @ WkT^T + bk
  gemm8<1, 1, 0><<<dim3(512), blk8, 0, stream>>>(
      xk, wkt, kb, bk, nullptr, D_, D_, 1.0f, 0, 0, 0, 128, 4);
  // VT_b[e][l] = sum_d WvT[e][d]*value_b[l][d] + bv[e]  [1024 x 2048] x16  gm=4 gn=8
  gemm8<1, 2, 0><<<dim3(512), blk8, 0, stream>>>(
      wvt, xv, vt, bv, nullptr, L_, D_, 1.0f,
      0, (long long)L_ * D_, (long long)D_ * L_, 4, 8);
  // S_b = Q_b @ K_b^T * scale  [2048 x 2048] x16  gm=8 gn=8 -> 1024 wgs
  gemm8<1, 0, 0><<<dim3(1024), blk8, 0, stream>>>(
      qb, kb, sp, nullptr, nullptr, L_, D_, QK_SCALE,
      (long long)L_ * D_, (long long)L_ * D_, (long long)L_ * L_, 8, 8);
  // P = softmax(S) rows, in place
  softmax_rows<<<BLROWS, blk, 0, stream>>>(sp);
  // ctx_b = P_b @ VT_b^T  [2048 x 1024] x16  gm=8 gn=4 -> 512 wgs
  gemm8<1, 0, 0><<<dim3(512), blk8, 0, stream>>>(
      sp, vt, ctx, nullptr, nullptr, D_, L_, 1.0f,
      (long long)L_ * L_, (long long)D_ * L_, (long long)L_ * D_, 8, 4);
  // out = ctx @ WoT^T + bo + residual(query)  fp32 [32768 x 1024]
  gemm8<0, 1, 1><<<dim3(512), blk8, 0, stream>>>(
      ctx, wot, out, bo, query, D_, D_, 1.0f, 0, 0, 0, 128, 4);

  (void)in_sizes; (void)n_in; (void)out_size; (void)ws_size;
}